// Round 8
// baseline (338.112 us; speedup 1.0000x reference)
//
#include <hip/hip_runtime.h>
#include <hip/hip_bf16.h>

#define HIDDEN  128
#define NUM_RBF 50
#define CUTOFF  5.0f
#define INV_WIDTH (49.0f / 5.0f)
#define OFF_STEP  (5.0f / 49.0f)
#define PI_F 3.14159265358979f

typedef __attribute__((ext_vector_type(8))) short short8;   // 8 bf16 (4 VGPR)
typedef __attribute__((ext_vector_type(4))) float floatx4;  // MFMA acc

// round-half-up bf16 conversion: 2 VALU ops (extra error <= 1/2 ULP on staged
// intermediates only — absmax margin 0.031 vs 0.108 threshold).
__device__ __forceinline__ unsigned short f2bf(float x) {
    union { float f; unsigned int u; } v; v.f = x;
    return (unsigned short)((v.u + 0x8000u) >> 16);
}

// unpack one bf16 of a packed pair to float (hi is compile-time)
__device__ __forceinline__ float bfpair(unsigned int p, int hi) {
    union { unsigned int u; float f; } v;
    v.u = hi ? (p & 0xffff0000u) : (p << 16);
    return v.f;
}

__device__ __forceinline__ float silu(float x) {
    return x / (1.0f + __expf(-x));
}

// XOR-swizzled half-index into a [rows][128] bf16 tile (256B rows): 16B slots
// XORed with row&7 (m201 st_16x32 pattern) — fragment reads land ~2-way
// bank-aliased (free per m136) with NO padding.
__device__ __forceinline__ int swz(int row, int k) {
    return (row << 7) + (((k >> 3) ^ (row & 7)) << 3) + (k & 7);
}

// same for [rows][64] bf16 tiles (128B rows: XOR row&7 over the 8 16B slots).
__device__ __forceinline__ int swz64(int row, int k) {
    return (row << 6) + (((k >> 3) ^ (row & 7)) << 3) + (k & 7);
}

// ---------------------------------------------------------------------------
// Counting-sort pipeline (scratch lives in d_out; node kernel overwrites d_out
// only at the very end). Hierarchical scan: local 256-bin scans + top scan.
// ---------------------------------------------------------------------------
__global__ void hist_kernel(const int* __restrict__ ei, int* __restrict__ cnt,
                            int n_nodes, int n_edges)
{
    for (int e = blockIdx.x * blockDim.x + threadIdx.x; e < n_edges;
         e += gridDim.x * blockDim.x) {
        const int r = min(max(ei[e], 0), n_nodes - 1);
        atomicAdd(&cnt[r], 1);
    }
}

__global__ __launch_bounds__(256) void scanA_kernel(const int* __restrict__ cnt,
                                                    int* __restrict__ cursor,
                                                    int* __restrict__ btot,
                                                    int nb)
{
    __shared__ int s[256];
    const int t = threadIdx.x;
    const int i = blockIdx.x * 256 + t;
    const int v = (i < nb) ? cnt[i] : 0;
    s[t] = v;
    __syncthreads();
#pragma unroll
    for (int off = 1; off < 256; off <<= 1) {
        const int u = (t >= off) ? s[t - off] : 0;
        __syncthreads();
        s[t] += u;
        __syncthreads();
    }
    if (i < nb) cursor[i] = s[t] - v;           // local exclusive prefix
    if (t == 255) btot[blockIdx.x] = s[255];    // segment total
}

__global__ __launch_bounds__(256) void scanB_kernel(const int* __restrict__ btot,
                                                    int* __restrict__ boff,
                                                    int nblk)
{
    __shared__ int s[256];
    const int t = threadIdx.x;
    const int v = (t < nblk) ? btot[t] : 0;
    s[t] = v;
    __syncthreads();
#pragma unroll
    for (int off = 1; off < 256; off <<= 1) {
        const int u = (t >= off) ? s[t - off] : 0;
        __syncthreads();
        s[t] += u;
        __syncthreads();
    }
    if (t < nblk) boff[t] = s[t] - v;
}

// One 16B record per sorted edge: {row, col, dist, pad}.
__global__ void scatter_kernel(const int* __restrict__ ei,
                               const float* __restrict__ pos,
                               int* __restrict__ cursor,
                               const int* __restrict__ boff,
                               float4* __restrict__ emeta,
                               int n_nodes, int n_edges)
{
    for (int e = blockIdx.x * blockDim.x + threadIdx.x; e < n_edges;
         e += gridDim.x * blockDim.x) {
        const int r = min(max(ei[e], 0), n_nodes - 1);
        const int c = min(max(ei[n_edges + e], 0), n_nodes - 1);
        const float dx = pos[r * 3 + 0] - pos[c * 3 + 0];
        const float dy = pos[r * 3 + 1] - pos[c * 3 + 1];
        const float dz = pos[r * 3 + 2] - pos[c * 3 + 2];
        const float dist = sqrtf(dx * dx + dy * dy + dz * dz + 1e-8f);
        const int p = boff[r >> 8] + atomicAdd(&cursor[r], 1);
        emeta[p] = make_float4(__int_as_float(r), __int_as_float(c), dist, 0.0f);
    }
}

// h pre-pack: bf16 channel-paired table hpk[node][64], hpk[node*64+p*16+l] =
// pack(h[node][p*32+16+l], h[node][p*32+l]). The edge gather then needs ONE
// dword per 2 channels (16 loads/lane/tile instead of 32, bytes halved) with
// ZERO added rounding error (h was rounded to bf16 in-register anyway).
__global__ void hpack_kernel(const float* __restrict__ h,
                             unsigned int* __restrict__ hpk, int n_nodes)
{
    const int total = n_nodes * 64;
    for (int i = blockIdx.x * blockDim.x + threadIdx.x; i < total;
         i += gridDim.x * blockDim.x) {
        const int node = i >> 6, t = i & 63, p = t >> 4, l = t & 15;
        const float f0 = h[node * HIDDEN + p * 32 + l];
        const float f1 = h[node * HIDDEN + p * 32 + 16 + l];
        hpk[i] = ((unsigned int)f2bf(f1) << 16) | (unsigned int)f2bf(f0);
    }
}

// ---------------------------------------------------------------------------
// Edge kernel: 512 thr = 8 waves, grid 512, launch_bounds(512,2) -> VGPR cap
// 128 (the only honored cap spelling; waves_per_eu(3)/(3,3) and bounds-of-1
// all spill — rounds 5-7). LDS 64KB: fw2T 32K + fw1T 16K + 8x2K walk buf.
//
// OPERAND-SWAP layer 1 (new): A-frag and B-frag share per-lane indexing
// (l15, quad*8+j), so mfma(fw1_frag, rbf_frag) computes Y[edge=col][chan=row]
// — lane (l15,q) gets, for its edge l15, channels {16nt+4q+r}. With the
// layer-2 contraction order sigma(q,j,m) = 16*(2m+(j>>2)) + 4q + (j&3)
// (absorbed into fw2T staging; read addresses unchanged), those values pack
// DIRECTLY into layer-2 A-frags in registers: the 32 ds_write + 4 ds_read
// tbuf round-trip per tile is deleted. fb1 folds into augmented RBF row
// k=50 (a1 value 1.0, fw1T row 50 := fb1) — no per-(q,r) bias registers.
// tbuf now only stages the final message for the segmented walk (2KB/wave).
// Spill tripwire: FETCH ~80MB (with hpk), WRITE ~43MB.
// ---------------------------------------------------------------------------
template<bool SORTED>
__global__ __launch_bounds__(512, 2) void edge_mfma_kernel(
    const float* __restrict__ h,
    const unsigned int* __restrict__ hpk,
    const float* __restrict__ pos,
    const int* __restrict__ ei,
    const float4* __restrict__ emeta,
    const float* __restrict__ fw1,
    const float* __restrict__ fb1,
    const float* __restrict__ fw2,
    const float* __restrict__ fb2,
    float* __restrict__ agg,
    int n_nodes, int n_edges)
{
    __shared__ __attribute__((aligned(16))) unsigned short fw2T[128 * 128];
    __shared__ __attribute__((aligned(16))) unsigned short fw1T[128 * 64];
    __shared__ __attribute__((aligned(16))) unsigned short tbuf[8 * 16 * 64];

    const int tid  = threadIdx.x;
    const int wave = tid >> 6;
    const int lane = tid & 63;
    const int l15  = lane & 15;
    const int quad = lane >> 4;

    // stage fw2 transposed + K-PERMUTED + swizzled: for read index
    // k' = m*32 + 8q + j, value = fw2[sigma(q,j,m)][n].
    for (int idx = tid; idx < HIDDEN * HIDDEN; idx += 512) {
        const int kp = idx >> 7, n = idx & 127;
        const int m = kp >> 5, q = (kp >> 3) & 3, j = kp & 7;
        const int src_k = 16 * (2 * m + (j >> 2)) + 4 * q + (j & 3);
        fw2T[swz(n, kp)] = f2bf(fw2[src_k * HIDDEN + n]);
    }
    // stage fw1 transposed+swizzled; row k=50 := fb1 (bias row), rows>50 zero
    for (int idx = tid; idx < HIDDEN * 64; idx += 512) {
        const int n = idx >> 6, k = idx & 63;
        const float v = (k < NUM_RBF) ? fw1[k * HIDDEN + n]
                      : (k == NUM_RBF ? fb1[n] : 0.0f);
        fw1T[swz64(n, k)] = f2bf(v);
    }

    // fb2 packed bf16 (4 VGPR)
    unsigned int fb2p[4];
#pragma unroll
    for (int p = 0; p < 4; ++p) {
        fb2p[p] = ((unsigned int)f2bf(fb2[(p * 2 + 1) * 16 + l15]) << 16) |
                  (unsigned int)f2bf(fb2[(p * 2) * 16 + l15]);
    }

    __syncthreads();   // fw2T/fw1T ready; no barriers inside the loop

    unsigned short* twave = &tbuf[wave * 16 * 64];
    const int tiles = (n_edges + 15) >> 4;
    const int tstride = gridDim.x * 8;
    int tile = blockIdx.x * 8 + wave;

    // ---- prefetch first tile's meta (sorted path) ----
    float4 nm = make_float4(0.0f, 0.0f, 0.0f, 0.0f);
    bool   nval = false;
    if (SORTED && tile < tiles) {
        const int e = tile * 16 + l15;
        nval = (e < n_edges);
        nm = emeta[min(e, n_edges - 1)];
    }

    for (; tile < tiles; tile += tstride) {
        // ---- edge meta: lane handles edge m = l15 (x4 redundant) ----
        int row, col; float dist; bool valid;
        if (SORTED) {
            row = __float_as_int(nm.x); col = __float_as_int(nm.y);
            dist = nm.z; valid = nval;
            const int tn = tile + tstride;
            if (tn < tiles) {
                const int e = tn * 16 + l15;
                nval = (e < n_edges);
                nm = emeta[min(e, n_edges - 1)];
            }
        } else {
            const int e = tile * 16 + l15;
            valid = (e < n_edges);
            const int eidx = valid ? e : (n_edges - 1);
            row = min(max(ei[eidx], 0), n_nodes - 1);
            col = min(max(ei[n_edges + eidx], 0), n_nodes - 1);
            const float dx = pos[row * 3 + 0] - pos[col * 3 + 0];
            const float dy = pos[row * 3 + 1] - pos[col * 3 + 1];
            const float dz = pos[row * 3 + 2] - pos[col * 3 + 2];
            dist = sqrtf(dx * dx + dy * dy + dz * dz + 1e-8f);
        }
        const float cut = (valid && dist <= CUTOFF)
            ? 0.5f * (__cosf(PI_F * dist * (1.0f / CUTOFF)) + 1.0f) : 0.0f;

        // broadcast to C-layout owners (edge = quad*4 + r) via shfl
        int mrow[4], mcol[4]; float mcut[4];
#pragma unroll
        for (int r = 0; r < 4; ++r) {
            const int src = quad * 4 + r;      // lanes 0..15 hold edges 0..15
            if (!SORTED) mrow[r] = __shfl(row, src);
            mcol[r] = __shfl(col, src);
            mcut[r] = __shfl(cut, src);
        }

        // ---- EARLY h gather: packed bf16 table (1 dword / 2 chans) ----
        unsigned int hv2[4][4];
        if (hpk != nullptr) {
#pragma unroll
            for (int r = 0; r < 4; ++r) {
                const unsigned int* hp = &hpk[(size_t)mcol[r] * 64 + l15];
#pragma unroll
                for (int p = 0; p < 4; ++p)
                    hv2[r][p] = hp[p * 16];
            }
        } else {
#pragma unroll
            for (int r = 0; r < 4; ++r) {
                const float* hp = &h[(size_t)mcol[r] * HIDDEN + l15];
#pragma unroll
                for (int p = 0; p < 4; ++p) {
                    const float f0 = hp[p * 32];
                    const float f1 = hp[p * 32 + 16];
                    hv2[r][p] = ((unsigned int)f2bf(f1) << 16) |
                                (unsigned int)f2bf(f0);
                }
            }
        }

        // ---- A1 fragments: RBFs in-register; k==50 is the BIAS row (1.0) ----
        short8 a1[2];
#pragma unroll
        for (int kit = 0; kit < 2; ++kit) {
            short8 f;
#pragma unroll
            for (int j = 0; j < 8; ++j) {
                const int k = kit * 32 + quad * 8 + j;
                const float x = (dist - OFF_STEP * (float)k) * INV_WIDTH;
                const float rv = (k < NUM_RBF) ? __expf(-0.5f * x * x)
                               : (k == NUM_RBF ? 1.0f : 0.0f);
                f[j] = (short)f2bf(rv);
            }
            a1[kit] = f;
        }

        // ---- layer 1 SWAPPED: mfma(fw1_frag, a1) -> Y[edge=col][chan=row].
        // Lane (l15,q) gets chans 16nt+4q+r for edge l15; silu+f2bf packs
        // straight into layer-2 A-frags (sigma order) — no LDS round-trip.
        short8 a2[4];
#pragma unroll
        for (int m = 0; m < 4; ++m) {
            union { short8 v; unsigned int u[4]; } pk;
#pragma unroll
            for (int s = 0; s < 2; ++s) {
                const int nt = 2 * m + s;
                const short8 wA =
                    *(const short8*)&fw1T[swz64(nt * 16 + l15, quad * 8)];
                const short8 wB =
                    *(const short8*)&fw1T[swz64(nt * 16 + l15, 32 + quad * 8)];
                floatx4 c = {0.0f, 0.0f, 0.0f, 0.0f};
                c = __builtin_amdgcn_mfma_f32_16x16x32_bf16(wA, a1[0], c, 0, 0, 0);
                c = __builtin_amdgcn_mfma_f32_16x16x32_bf16(wB, a1[1], c, 0, 0, 0);
                pk.u[2 * s] =
                    ((unsigned int)f2bf(silu(c[1])) << 16) |
                    (unsigned int)f2bf(silu(c[0]));
                pk.u[2 * s + 1] =
                    ((unsigned int)f2bf(silu(c[3])) << 16) |
                    (unsigned int)f2bf(silu(c[2]));
            }
            a2[m] = pk.v;
        }

        // ---- walk mask (computed once, used by both half-walks) ----
        unsigned int mask = 0;
        if (SORTED) {
            const int pr = __shfl(row, (l15 > 0) ? (l15 - 1) : 0);
            const unsigned long long bal =
                __ballot((l15 > 0) && (row != pr));
            mask = (unsigned int)bal & 0xFFFFu;
        }

        // ---- layer 2 + cutoff*h epilogue, per 64-chan half; segmented walk
        // after each half (lane owns 1 chan per walk) ----
#pragma unroll
        for (int half = 0; half < 2; ++half) {
#pragma unroll
            for (int nt2 = 0; nt2 < 4; ++nt2) {
                const int nt = half * 4 + nt2;
                const float b0 = bfpair(fb2p[nt >> 1], nt & 1);
                floatx4 c = {b0, b0, b0, b0};
#pragma unroll
                for (int m = 0; m < 4; ++m) {
                    const short8 b =
                        *(const short8*)&fw2T[swz(nt * 16 + l15, m * 32 + quad * 8)];
                    c = __builtin_amdgcn_mfma_f32_16x16x32_bf16(a2[m], b, c, 0, 0, 0);
                }
                const int chan = nt * 16 + l15;
#pragma unroll
                for (int r = 0; r < 4; ++r) {
                    const float val = c[r] * mcut[r] * bfpair(hv2[r][nt >> 1], nt & 1);
                    if (SORTED) {
                        twave[swz64(quad * 4 + r, nt2 * 16 + l15)] = f2bf(val);
                    } else {
                        atomicAdd(&agg[mrow[r] * HIDDEN + chan], val);
                    }
                }
            }

            if (SORTED) {
                const int gchan = half * 64 + lane;   // this lane's channel
                float acc = 0.0f;
                int prow = __shfl(row, 0);
#pragma unroll
                for (int i = 0; i < 16; ++i) {
                    union { unsigned int u; float f; } v;
                    v.u = (unsigned int)twave[swz64(i, lane)] << 16;
                    if (mask & (1u << i)) {           // wave-uniform branch
                        atomicAdd(&agg[prow * HIDDEN + gchan], acc);
                        acc = 0.0f;
                        prow = __shfl(row, i);
                    }
                    acc += v.f;
                }
                atomicAdd(&agg[prow * HIDDEN + gchan], acc);
            }
        }
    }
}

// ---------------------------------------------------------------------------
// Node kernel (MFMA): out = h + silu(agg@iw1+b1)@iw2+b2. Grid 256 (staging
// amortization: 512 grid showed no gain in r7).
// ---------------------------------------------------------------------------
__global__ __launch_bounds__(256) void node_mfma_kernel(
    const float* __restrict__ h,
    const float* __restrict__ agg,
    const float* __restrict__ iw1,
    const float* __restrict__ ib1,
    const float* __restrict__ iw2,
    const float* __restrict__ ib2,
    float* __restrict__ out,
    int n_nodes)
{
    __shared__ __attribute__((aligned(16))) unsigned short w2T[128 * 128];
    __shared__ __attribute__((aligned(16))) unsigned short tbuf[4 * 16 * 128];

    const int tid  = threadIdx.x;
    const int wave = tid >> 6;
    const int lane = tid & 63;
    const int l15  = lane & 15;
    const int quad = lane >> 4;

    for (int idx = tid; idx < HIDDEN * HIDDEN; idx += 256) {
        const int k = idx >> 7, n = idx & 127;
        w2T[swz(n, k)] = f2bf(iw2[idx]);
    }

    short8 b1[4][8];
#pragma unroll
    for (int kit = 0; kit < 4; ++kit)
#pragma unroll
        for (int nt = 0; nt < 8; ++nt) {
            short8 f;
#pragma unroll
            for (int j = 0; j < 8; ++j) {
                const int k = kit * 32 + quad * 8 + j;
                f[j] = (short)f2bf(iw1[k * HIDDEN + nt * 16 + l15]);
            }
            b1[kit][nt] = f;
        }

    float ib1v[8], ib2v[8];
#pragma unroll
    for (int nt = 0; nt < 8; ++nt) {
        ib1v[nt] = ib1[nt * 16 + l15];
        ib2v[nt] = ib2[nt * 16 + l15];
    }

    __syncthreads();

    unsigned short* twave = &tbuf[wave * 16 * 128];
    const int tiles = (n_nodes + 15) >> 4;

    for (int tile = blockIdx.x * 4 + wave; tile < tiles; tile += gridDim.x * 4) {
        const int m0 = tile * 16;

        const int mA = min(m0 + l15, n_nodes - 1);
        short8 a1[4];
#pragma unroll
        for (int kit = 0; kit < 4; ++kit) {
            const float* p = &agg[(size_t)mA * HIDDEN + kit * 32 + quad * 8];
            short8 f;
#pragma unroll
            for (int j = 0; j < 8; ++j) f[j] = (short)f2bf(p[j]);
            a1[kit] = f;
        }

        int mo[4]; float hres[4][8];
#pragma unroll
        for (int r = 0; r < 4; ++r) {
            mo[r] = m0 + quad * 4 + r;
            const int mc = min(mo[r], n_nodes - 1);
#pragma unroll
            for (int nt = 0; nt < 8; ++nt)
                hres[r][nt] = h[(size_t)mc * HIDDEN + nt * 16 + l15];
        }

#pragma unroll
        for (int nt = 0; nt < 8; ++nt) {
            floatx4 c = {ib1v[nt], ib1v[nt], ib1v[nt], ib1v[nt]};
#pragma unroll
            for (int kit = 0; kit < 4; ++kit)
                c = __builtin_amdgcn_mfma_f32_16x16x32_bf16(a1[kit], b1[kit][nt], c, 0, 0, 0);
#pragma unroll
            for (int r = 0; r < 4; ++r)
                twave[swz(quad * 4 + r, nt * 16 + l15)] = f2bf(silu(c[r]));
        }

        short8 a2[4];
#pragma unroll
        for (int kit = 0; kit < 4; ++kit)
            a2[kit] = *(const short8*)&twave[swz(l15, kit * 32 + quad * 8)];

#pragma unroll
        for (int nt = 0; nt < 8; ++nt) {
            floatx4 c = {ib2v[nt], ib2v[nt], ib2v[nt], ib2v[nt]};
#pragma unroll
            for (int kit = 0; kit < 4; ++kit) {
                const short8 b =
                    *(const short8*)&w2T[swz(nt * 16 + l15, kit * 32 + quad * 8)];
                c = __builtin_amdgcn_mfma_f32_16x16x32_bf16(a2[kit], b, c, 0, 0, 0);
            }
            const int chan = nt * 16 + l15;
#pragma unroll
            for (int r = 0; r < 4; ++r)
                if (mo[r] < n_nodes)
                    out[(size_t)mo[r] * HIDDEN + chan] = hres[r][nt] + c[r];
        }
    }
}

extern "C" void kernel_launch(void* const* d_in, const int* in_sizes, int n_in,
                              void* d_out, int out_size, void* d_ws, size_t ws_size,
                              hipStream_t stream)
{
    const float* h   = (const float*)d_in[0];
    const float* pos = (const float*)d_in[1];
    const int*   ei  = (const int*)d_in[2];
    const float* fw1 = (const float*)d_in[3];
    const float* fb1 = (const float*)d_in[4];
    const float* fw2 = (const float*)d_in[5];
    const float* fb2 = (const float*)d_in[6];
    const float* iw1 = (const float*)d_in[7];
    const float* ib1 = (const float*)d_in[8];
    const float* iw2 = (const float*)d_in[9];
    const float* ib2 = (const float*)d_in[10];
    float* out = (float*)d_out;

    const int n_nodes = in_sizes[0] / HIDDEN;
    const int n_edges = in_sizes[2] / 2;
    const int nscan   = (n_nodes + 255) >> 8;   // scanA blocks (<=256 required)

    const size_t need = (size_t)n_nodes * HIDDEN * sizeof(float);
    const bool use_ws = (d_ws != nullptr) && (ws_size >= need);

    // sort scratch layout in d_out (ints): cnt[nb] cursor[nb] btot[256]
    // boff[256] emeta[4E] hpk[64*nb]  (emeta/hpk 16B-aligned)
    const size_t moff = (((size_t)2 * n_nodes + 512) + 3) & ~(size_t)3;
    const size_t hoff = moff + (size_t)4 * n_edges;     // hpk offset (ints)
    const size_t sort_ints = hoff;                       // sort without hpk
    const size_t full_ints = hoff + (size_t)64 * n_nodes;
    const bool can_sort = use_ws && nscan <= 256 &&
                          ((size_t)out_size >= sort_ints);
    const bool can_hpk  = can_sort && ((size_t)out_size >= full_ints);

    if (can_sort) {
        float*  agg    = (float*)d_ws;
        int*    base   = (int*)d_out;
        int*    cnt    = base;
        int*    cursor = base + n_nodes;
        int*    btot   = base + 2 * n_nodes;
        int*    boff   = btot + 256;
        float4* emeta  = (float4*)(base + moff);
        unsigned int* hpk = can_hpk ? (unsigned int*)(base + hoff) : nullptr;

        hipMemsetAsync(cnt, 0, (size_t)n_nodes * sizeof(int), stream);
        hipMemsetAsync(agg, 0, need, stream);

        hist_kernel<<<1024, 256, 0, stream>>>(ei, cnt, n_nodes, n_edges);
        scanA_kernel<<<nscan, 256, 0, stream>>>(cnt, cursor, btot, n_nodes);
        scanB_kernel<<<1, 256, 0, stream>>>(btot, boff, nscan);
        scatter_kernel<<<1024, 256, 0, stream>>>(ei, pos, cursor, boff,
                                                 emeta, n_nodes, n_edges);
        if (can_hpk)
            hpack_kernel<<<1024, 256, 0, stream>>>(h, hpk, n_nodes);

        edge_mfma_kernel<true><<<512, 512, 0, stream>>>(
            h, hpk, pos, ei, emeta,
            fw1, fb1, fw2, fb2, agg, n_nodes, n_edges);

        node_mfma_kernel<<<256, 256, 0, stream>>>(h, agg, iw1, ib1, iw2, ib2,
                                                  out, n_nodes);
    } else {
        float* agg = use_ws ? (float*)d_ws : out;
        hipMemsetAsync(agg, 0, need, stream);
        edge_mfma_kernel<false><<<512, 512, 0, stream>>>(
            h, nullptr, pos, ei, nullptr,
            fw1, fb1, fw2, fb2, agg, n_nodes, n_edges);
        node_mfma_kernel<<<256, 256, 0, stream>>>(h, agg, iw1, ib1, iw2, ib2,
                                                  out, n_nodes);
    }
}

// Round 9
// 323.906 us; speedup vs baseline: 1.0439x; 1.0439x over previous
//
#include <hip/hip_runtime.h>
#include <hip/hip_bf16.h>

#define HIDDEN  128
#define NUM_RBF 50
#define CUTOFF  5.0f
#define INV_WIDTH (49.0f / 5.0f)
#define OFF_STEP  (5.0f / 49.0f)
#define PI_F 3.14159265358979f

typedef __attribute__((ext_vector_type(8))) short short8;   // 8 bf16 (4 VGPR)
typedef __attribute__((ext_vector_type(4))) float floatx4;  // MFMA acc

// round-half-up bf16 conversion: 2 VALU ops (extra error <= 1/2 ULP on staged
// intermediates only — absmax margin 0.031 vs 0.108 threshold).
__device__ __forceinline__ unsigned short f2bf(float x) {
    union { float f; unsigned int u; } v; v.f = x;
    return (unsigned short)((v.u + 0x8000u) >> 16);
}

// unpack one bf16 of a packed pair to float (hi is compile-time)
__device__ __forceinline__ float bfpair(unsigned int p, int hi) {
    union { unsigned int u; float f; } v;
    v.u = hi ? (p & 0xffff0000u) : (p << 16);
    return v.f;
}

__device__ __forceinline__ float silu(float x) {
    return x / (1.0f + __expf(-x));
}

// XOR-swizzled half-index into a [rows][128] bf16 tile (256B rows): 16B slots
// XORed with row&7 (m201 st_16x32 pattern) — fragment reads land ~2-way
// bank-aliased (free per m136) with NO padding.
__device__ __forceinline__ int swz(int row, int k) {
    return (row << 7) + (((k >> 3) ^ (row & 7)) << 3) + (k & 7);
}

// same for [rows][64] bf16 tiles (128B rows: XOR row&7 over the 8 16B slots).
__device__ __forceinline__ int swz64(int row, int k) {
    return (row << 6) + (((k >> 3) ^ (row & 7)) << 3) + (k & 7);
}

// ---------------------------------------------------------------------------
// Counting-sort pipeline (scratch lives in d_out; node kernel overwrites d_out
// only at the very end). r9: scanA+scanB fused into ONE single-block kernel
// producing GLOBAL exclusive prefixes (scatter needs no boff) — 2 launches
// saved vs r8 (this + dropped hpack).
// ---------------------------------------------------------------------------
__global__ void hist_kernel(const int* __restrict__ ei, int* __restrict__ cnt,
                            int n_nodes, int n_edges)
{
    for (int e = blockIdx.x * blockDim.x + threadIdx.x; e < n_edges;
         e += gridDim.x * blockDim.x) {
        const int r = min(max(ei[e], 0), n_nodes - 1);
        atomicAdd(&cnt[r], 1);
    }
}

// Single block, 256 threads: thread t serially scans bins [t*L,(t+1)*L);
// Hillis-Steele over per-thread totals; second pass writes cursor[i] =
// GLOBAL exclusive prefix. ~200 bins/thread, loads pipeline (sum chain is
// register-fast) — a few us, replaces two dispatches.
__global__ __launch_bounds__(256) void scan_kernel(const int* __restrict__ cnt,
                                                   int* __restrict__ cursor,
                                                   int nb)
{
    __shared__ int s[256];
    const int t = threadIdx.x;
    const int L = (nb + 255) >> 8;
    const int lo = t * L;
    const int hi = min(lo + L, nb);

    int sum = 0;
#pragma unroll 4
    for (int i = lo; i < hi; ++i) sum += cnt[i];
    s[t] = sum;
    __syncthreads();
#pragma unroll
    for (int off = 1; off < 256; off <<= 1) {
        const int u = (t >= off) ? s[t - off] : 0;
        __syncthreads();
        s[t] += u;
        __syncthreads();
    }
    int run = s[t] - sum;   // global exclusive base for this thread's range
#pragma unroll 4
    for (int i = lo; i < hi; ++i) {
        const int c = cnt[i];
        cursor[i] = run;
        run += c;
    }
}

// One 16B record per sorted edge: {row, col, dist, pad}. cursor holds global
// exclusive prefixes, so the slot is a single atomic post-increment.
__global__ void scatter_kernel(const int* __restrict__ ei,
                               const float* __restrict__ pos,
                               int* __restrict__ cursor,
                               float4* __restrict__ emeta,
                               int n_nodes, int n_edges)
{
    for (int e = blockIdx.x * blockDim.x + threadIdx.x; e < n_edges;
         e += gridDim.x * blockDim.x) {
        const int r = min(max(ei[e], 0), n_nodes - 1);
        const int c = min(max(ei[n_edges + e], 0), n_nodes - 1);
        const float dx = pos[r * 3 + 0] - pos[c * 3 + 0];
        const float dy = pos[r * 3 + 1] - pos[c * 3 + 1];
        const float dz = pos[r * 3 + 2] - pos[c * 3 + 2];
        const float dist = sqrtf(dx * dx + dy * dy + dz * dz + 1e-8f);
        const int p = atomicAdd(&cursor[r], 1);
        emeta[p] = make_float4(__int_as_float(r), __int_as_float(c), dist, 0.0f);
    }
}

// ---------------------------------------------------------------------------
// Edge kernel: 512 thr = 8 waves, grid 256 = exactly 1 block/CU (r4/r7 proven
// body at 139us; r8's operand-swap/in-reg-a2 regressed to 147 — reverted).
// launch_bounds(512,2) is the ONLY honored VGPR-cap spelling (cap 128;
// waves_per_eu(3)/(3,3)/bounds-1 all spill — rounds 5-7).
// LDS 64KB: fw2T 32K + fw1T 16K + 8x2K walk buf.
//
// r9 changes:
//  * fb1 folded into fw1T bias row k=50 (a1 value 1.0) — r8-proven, -4 VGPR.
//  * CONTIGUOUS balanced tile range per wave + CARRY walk: (prow,accA,accB)
//    persist across tiles; flush only on true row transitions (~1.25/tile
//    instead of ~2.25). WRITE tripwire: ~43 -> ~28-32MB.
// Spill tripwire: FETCH ~140MB, VGPR<=128.
// ---------------------------------------------------------------------------
template<bool SORTED>
__global__ __launch_bounds__(512, 2) void edge_mfma_kernel(
    const float* __restrict__ h,
    const float* __restrict__ pos,
    const int* __restrict__ ei,
    const float4* __restrict__ emeta,
    const float* __restrict__ fw1,
    const float* __restrict__ fb1,
    const float* __restrict__ fw2,
    const float* __restrict__ fb2,
    float* __restrict__ agg,
    int n_nodes, int n_edges)
{
    __shared__ __attribute__((aligned(16))) unsigned short fw2T[128 * 128];
    __shared__ __attribute__((aligned(16))) unsigned short fw1T[128 * 64];
    __shared__ __attribute__((aligned(16))) unsigned short tbuf[8 * 16 * 64];

    const int tid  = threadIdx.x;
    const int wave = tid >> 6;
    const int lane = tid & 63;
    const int l15  = lane & 15;
    const int quad = lane >> 4;

    // stage fw2 transposed+swizzled (bf16): fw2T[(n,k)] = fw2[k][n]
    for (int idx = tid; idx < HIDDEN * HIDDEN; idx += 512) {
        const int k = idx >> 7, n = idx & 127;
        fw2T[swz(n, k)] = f2bf(fw2[idx]);
    }
    // stage fw1 transposed+swizzled; row k=50 := fb1 (bias row), rows>50 zero
    for (int idx = tid; idx < HIDDEN * 64; idx += 512) {
        const int n = idx >> 6, k = idx & 63;
        const float v = (k < NUM_RBF) ? fw1[k * HIDDEN + n]
                      : (k == NUM_RBF ? fb1[n] : 0.0f);
        fw1T[swz64(n, k)] = f2bf(v);
    }

    // fb2 packed bf16 (4 VGPR)
    unsigned int fb2p[4];
#pragma unroll
    for (int p = 0; p < 4; ++p) {
        fb2p[p] = ((unsigned int)f2bf(fb2[(p * 2 + 1) * 16 + l15]) << 16) |
                  (unsigned int)f2bf(fb2[(p * 2) * 16 + l15]);
    }

    __syncthreads();   // fw2T/fw1T ready; no barriers inside the loop

    unsigned short* twave = &tbuf[wave * 16 * 64];
    const int tiles = (n_edges + 15) >> 4;

    // balanced CONTIGUOUS range for this wave
    const int nw  = gridDim.x * 8;
    const int wid = blockIdx.x * 8 + wave;
    const int qt  = tiles / nw, rmd = tiles % nw;
    const int t0  = wid * qt + min(wid, rmd);
    const int t1  = t0 + qt + (wid < rmd ? 1 : 0);

    // ---- prefetch first tile's meta (sorted path) ----
    float4 nm = make_float4(0.0f, 0.0f, 0.0f, 0.0f);
    bool   nval = false;
    if (SORTED && t0 < t1) {
        const int e = t0 * 16 + l15;
        nval = (e < n_edges);
        nm = emeta[min(e, n_edges - 1)];
    }

    // carry state (wave-uniform prow; per-lane half-channel accumulators)
    int prow = -1;
    float accA = 0.0f, accB = 0.0f;

    for (int tile = t0; tile < t1; ++tile) {
        // ---- edge meta: lane handles edge m = l15 (x4 redundant) ----
        int row, col; float dist; bool valid;
        if (SORTED) {
            row = __float_as_int(nm.x); col = __float_as_int(nm.y);
            dist = nm.z; valid = nval;
            const int tn = tile + 1;
            if (tn < t1) {
                const int e = tn * 16 + l15;
                nval = (e < n_edges);
                nm = emeta[min(e, n_edges - 1)];
            }
        } else {
            const int e = tile * 16 + l15;
            valid = (e < n_edges);
            const int eidx = valid ? e : (n_edges - 1);
            row = min(max(ei[eidx], 0), n_nodes - 1);
            col = min(max(ei[n_edges + eidx], 0), n_nodes - 1);
            const float dx = pos[row * 3 + 0] - pos[col * 3 + 0];
            const float dy = pos[row * 3 + 1] - pos[col * 3 + 1];
            const float dz = pos[row * 3 + 2] - pos[col * 3 + 2];
            dist = sqrtf(dx * dx + dy * dy + dz * dz + 1e-8f);
        }
        const float cut = (valid && dist <= CUTOFF)
            ? 0.5f * (__cosf(PI_F * dist * (1.0f / CUTOFF)) + 1.0f) : 0.0f;

        // broadcast to C-layout owners (edge = quad*4 + r) via shfl
        int mrow[4], mcol[4]; float mcut[4];
#pragma unroll
        for (int r = 0; r < 4; ++r) {
            const int src = quad * 4 + r;      // lanes 0..15 hold edges 0..15
            if (!SORTED) mrow[r] = __shfl(row, src);
            mcol[r] = __shfl(col, src);
            mcut[r] = __shfl(cut, src);
        }

        // ---- EARLY h gather, packed to bf16 pairs (16 VGPR; the message is
        // rounded to bf16 downstream anyway) ----
        unsigned int hv2[4][4];
#pragma unroll
        for (int r = 0; r < 4; ++r) {
            const float* hp = &h[(size_t)mcol[r] * HIDDEN + l15];
#pragma unroll
            for (int p = 0; p < 4; ++p) {
                const float f0 = hp[p * 32];
                const float f1 = hp[p * 32 + 16];
                hv2[r][p] = ((unsigned int)f2bf(f1) << 16) |
                            (unsigned int)f2bf(f0);
            }
        }

        // ---- A1 fragments: RBFs in-register; k==50 is the BIAS row (1.0) ----
        short8 a1[2];
#pragma unroll
        for (int kit = 0; kit < 2; ++kit) {
            short8 f;
#pragma unroll
            for (int j = 0; j < 8; ++j) {
                const int k = kit * 32 + quad * 8 + j;
                const float x = (dist - OFF_STEP * (float)k) * INV_WIDTH;
                const float rv = (k < NUM_RBF) ? __expf(-0.5f * x * x)
                               : (k == NUM_RBF ? 1.0f : 0.0f);
                f[j] = (short)f2bf(rv);
            }
            a1[kit] = f;
        }

        // ---- layer 1 -> silu -> tbuf in TWO 64-chan halves; A2 frags pulled
        // into regs after each half (wave-private LDS store->read idiom) ----
        short8 a2[4];
#pragma unroll
        for (int half = 0; half < 2; ++half) {
#pragma unroll
            for (int nt2 = 0; nt2 < 4; ++nt2) {
                const int nt = half * 4 + nt2;
                const short8 bA =
                    *(const short8*)&fw1T[swz64(nt * 16 + l15, quad * 8)];
                const short8 bB =
                    *(const short8*)&fw1T[swz64(nt * 16 + l15, 32 + quad * 8)];
                floatx4 c = {0.0f, 0.0f, 0.0f, 0.0f};   // bias via k=50 row
                c = __builtin_amdgcn_mfma_f32_16x16x32_bf16(a1[0], bA, c, 0, 0, 0);
                c = __builtin_amdgcn_mfma_f32_16x16x32_bf16(a1[1], bB, c, 0, 0, 0);
#pragma unroll
                for (int r = 0; r < 4; ++r)
                    twave[swz64(quad * 4 + r, nt2 * 16 + l15)] = f2bf(silu(c[r]));
            }
            a2[half * 2]     = *(const short8*)&twave[swz64(l15, quad * 8)];
            a2[half * 2 + 1] = *(const short8*)&twave[swz64(l15, 32 + quad * 8)];
        }

        // ---- walk mask: bit i = (row[i] != row[i-1]), i>=1; i==0 boundary
        // is the runtime carry check vs prow ----
        unsigned int mask = 0;
        int r0 = 0;
        if (SORTED) {
            const int pr = __shfl(row, (l15 > 0) ? (l15 - 1) : 0);
            const unsigned long long bal =
                __ballot((l15 > 0) && (row != pr));
            mask = (unsigned int)bal & 0xFFFFu;
            r0 = __shfl(row, 0);
        }

        // ---- layer 2 + cutoff*h epilogue, per 64-chan half; carry walk ----
#pragma unroll
        for (int half = 0; half < 2; ++half) {
#pragma unroll
            for (int nt2 = 0; nt2 < 4; ++nt2) {
                const int nt = half * 4 + nt2;
                const float b0 = bfpair(fb2p[nt >> 1], nt & 1);
                floatx4 c = {b0, b0, b0, b0};
#pragma unroll
                for (int kit = 0; kit < 4; ++kit) {
                    const short8 b =
                        *(const short8*)&fw2T[swz(nt * 16 + l15, kit * 32 + quad * 8)];
                    c = __builtin_amdgcn_mfma_f32_16x16x32_bf16(a2[kit], b, c, 0, 0, 0);
                }
                const int chan = nt * 16 + l15;
#pragma unroll
                for (int r = 0; r < 4; ++r) {
                    const float val = c[r] * mcut[r] * bfpair(hv2[r][nt >> 1], nt & 1);
                    if (SORTED) {
                        twave[swz64(quad * 4 + r, nt2 * 16 + l15)] = f2bf(val);
                    } else {
                        atomicAdd(&agg[mrow[r] * HIDDEN + chan], val);
                    }
                }
            }

            if (SORTED) {
                const int gchan = half * 64 + lane;   // this lane's channel
                float acc = half ? accB : accA;
                int pr = prow;                        // both halves replay the
#pragma unroll                                        // same boundary sequence
                for (int i = 0; i < 16; ++i) {
                    union { unsigned int u; float f; } v;
                    v.u = (unsigned int)twave[swz64(i, lane)] << 16;
                    const bool bnd = (i == 0) ? (r0 != pr)
                                              : ((mask >> i) & 1u);
                    if (bnd) {                        // wave-uniform branch
                        if (pr >= 0)
                            atomicAdd(&agg[pr * HIDDEN + gchan], acc);
                        acc = 0.0f;
                        pr = __shfl(row, i);
                    }
                    acc += v.f;
                }
                if (half) { accB = acc; prow = pr; }
                else      { accA = acc; }
            }
        }
    }

    // ---- final carry flush ----
    if (SORTED && prow >= 0) {
        atomicAdd(&agg[prow * HIDDEN + lane],      accA);
        atomicAdd(&agg[prow * HIDDEN + 64 + lane], accB);
    }
}

// ---------------------------------------------------------------------------
// Node kernel (MFMA): out = h + silu(agg@iw1+b1)@iw2+b2. Grid 256.
// ---------------------------------------------------------------------------
__global__ __launch_bounds__(256) void node_mfma_kernel(
    const float* __restrict__ h,
    const float* __restrict__ agg,
    const float* __restrict__ iw1,
    const float* __restrict__ ib1,
    const float* __restrict__ iw2,
    const float* __restrict__ ib2,
    float* __restrict__ out,
    int n_nodes)
{
    __shared__ __attribute__((aligned(16))) unsigned short w2T[128 * 128];
    __shared__ __attribute__((aligned(16))) unsigned short tbuf[4 * 16 * 128];

    const int tid  = threadIdx.x;
    const int wave = tid >> 6;
    const int lane = tid & 63;
    const int l15  = lane & 15;
    const int quad = lane >> 4;

    for (int idx = tid; idx < HIDDEN * HIDDEN; idx += 256) {
        const int k = idx >> 7, n = idx & 127;
        w2T[swz(n, k)] = f2bf(iw2[idx]);
    }

    short8 b1[4][8];
#pragma unroll
    for (int kit = 0; kit < 4; ++kit)
#pragma unroll
        for (int nt = 0; nt < 8; ++nt) {
            short8 f;
#pragma unroll
            for (int j = 0; j < 8; ++j) {
                const int k = kit * 32 + quad * 8 + j;
                f[j] = (short)f2bf(iw1[k * HIDDEN + nt * 16 + l15]);
            }
            b1[kit][nt] = f;
        }

    float ib1v[8], ib2v[8];
#pragma unroll
    for (int nt = 0; nt < 8; ++nt) {
        ib1v[nt] = ib1[nt * 16 + l15];
        ib2v[nt] = ib2[nt * 16 + l15];
    }

    __syncthreads();

    unsigned short* twave = &tbuf[wave * 16 * 128];
    const int tiles = (n_nodes + 15) >> 4;

    for (int tile = blockIdx.x * 4 + wave; tile < tiles; tile += gridDim.x * 4) {
        const int m0 = tile * 16;

        const int mA = min(m0 + l15, n_nodes - 1);
        short8 a1[4];
#pragma unroll
        for (int kit = 0; kit < 4; ++kit) {
            const float* p = &agg[(size_t)mA * HIDDEN + kit * 32 + quad * 8];
            short8 f;
#pragma unroll
            for (int j = 0; j < 8; ++j) f[j] = (short)f2bf(p[j]);
            a1[kit] = f;
        }

        int mo[4]; float hres[4][8];
#pragma unroll
        for (int r = 0; r < 4; ++r) {
            mo[r] = m0 + quad * 4 + r;
            const int mc = min(mo[r], n_nodes - 1);
#pragma unroll
            for (int nt = 0; nt < 8; ++nt)
                hres[r][nt] = h[(size_t)mc * HIDDEN + nt * 16 + l15];
        }

#pragma unroll
        for (int nt = 0; nt < 8; ++nt) {
            floatx4 c = {ib1v[nt], ib1v[nt], ib1v[nt], ib1v[nt]};
#pragma unroll
            for (int kit = 0; kit < 4; ++kit)
                c = __builtin_amdgcn_mfma_f32_16x16x32_bf16(a1[kit], b1[kit][nt], c, 0, 0, 0);
#pragma unroll
            for (int r = 0; r < 4; ++r)
                twave[swz(quad * 4 + r, nt * 16 + l15)] = f2bf(silu(c[r]));
        }

        short8 a2[4];
#pragma unroll
        for (int kit = 0; kit < 4; ++kit)
            a2[kit] = *(const short8*)&twave[swz(l15, kit * 32 + quad * 8)];

#pragma unroll
        for (int nt = 0; nt < 8; ++nt) {
            floatx4 c = {ib2v[nt], ib2v[nt], ib2v[nt], ib2v[nt]};
#pragma unroll
            for (int kit = 0; kit < 4; ++kit) {
                const short8 b =
                    *(const short8*)&w2T[swz(nt * 16 + l15, kit * 32 + quad * 8)];
                c = __builtin_amdgcn_mfma_f32_16x16x32_bf16(a2[kit], b, c, 0, 0, 0);
            }
            const int chan = nt * 16 + l15;
#pragma unroll
            for (int r = 0; r < 4; ++r)
                if (mo[r] < n_nodes)
                    out[(size_t)mo[r] * HIDDEN + chan] = hres[r][nt] + c[r];
        }
    }
}

extern "C" void kernel_launch(void* const* d_in, const int* in_sizes, int n_in,
                              void* d_out, int out_size, void* d_ws, size_t ws_size,
                              hipStream_t stream)
{
    const float* h   = (const float*)d_in[0];
    const float* pos = (const float*)d_in[1];
    const int*   ei  = (const int*)d_in[2];
    const float* fw1 = (const float*)d_in[3];
    const float* fb1 = (const float*)d_in[4];
    const float* fw2 = (const float*)d_in[5];
    const float* fb2 = (const float*)d_in[6];
    const float* iw1 = (const float*)d_in[7];
    const float* ib1 = (const float*)d_in[8];
    const float* iw2 = (const float*)d_in[9];
    const float* ib2 = (const float*)d_in[10];
    float* out = (float*)d_out;

    const int n_nodes = in_sizes[0] / HIDDEN;
    const int n_edges = in_sizes[2] / 2;
    const int nscan   = (n_nodes + 255) >> 8;   // <=256 so one scan block works

    const size_t need = (size_t)n_nodes * HIDDEN * sizeof(float);
    const bool use_ws = (d_ws != nullptr) && (ws_size >= need);

    // sort scratch layout in d_out (ints): cnt[nb] cursor[nb] pad emeta[4E]
    const size_t moff = (((size_t)2 * n_nodes + 512) + 3) & ~(size_t)3;
    const size_t scratch_ints = moff + (size_t)4 * n_edges;
    const bool can_sort = use_ws && nscan <= 256 &&
                          ((size_t)out_size >= scratch_ints);

    if (can_sort) {
        float*  agg    = (float*)d_ws;
        int*    base   = (int*)d_out;
        int*    cnt    = base;
        int*    cursor = base + n_nodes;
        float4* emeta  = (float4*)(base + moff);

        hipMemsetAsync(cnt, 0, (size_t)n_nodes * sizeof(int), stream);
        hipMemsetAsync(agg, 0, need, stream);

        hist_kernel<<<1024, 256, 0, stream>>>(ei, cnt, n_nodes, n_edges);
        scan_kernel<<<1, 256, 0, stream>>>(cnt, cursor, n_nodes);
        scatter_kernel<<<1024, 256, 0, stream>>>(ei, pos, cursor,
                                                 emeta, n_nodes, n_edges);

        // 256 blocks x 8 waves = 1 block/CU; contiguous balanced tile ranges
        edge_mfma_kernel<true><<<256, 512, 0, stream>>>(
            h, pos, ei, emeta,
            fw1, fb1, fw2, fb2, agg, n_nodes, n_edges);

        node_mfma_kernel<<<256, 256, 0, stream>>>(h, agg, iw1, ib1, iw2, ib2,
                                                  out, n_nodes);
    } else {
        float* agg = use_ws ? (float*)d_ws : out;
        hipMemsetAsync(agg, 0, need, stream);
        edge_mfma_kernel<false><<<256, 512, 0, stream>>>(
            h, pos, ei, nullptr,
            fw1, fb1, fw2, fb2, agg, n_nodes, n_edges);
        node_mfma_kernel<<<256, 256, 0, stream>>>(h, agg, iw1, ib1, iw2, ib2,
                                                  out, n_nodes);
    }
}

// Round 10
// 300.323 us; speedup vs baseline: 1.1258x; 1.0785x over previous
//
#include <hip/hip_runtime.h>
#include <hip/hip_bf16.h>

#define HIDDEN  128
#define NUM_RBF 50
#define CUTOFF  5.0f
#define INV_WIDTH (49.0f / 5.0f)
#define OFF_STEP  (5.0f / 49.0f)
#define PI_F 3.14159265358979f

typedef __attribute__((ext_vector_type(8))) short short8;   // 8 bf16 (4 VGPR)
typedef __attribute__((ext_vector_type(4))) float floatx4;  // MFMA acc

// round-half-up bf16 conversion: 2 VALU ops (extra error <= 1/2 ULP on staged
// intermediates only — absmax margin 0.031 vs 0.108 threshold).
__device__ __forceinline__ unsigned short f2bf(float x) {
    union { float f; unsigned int u; } v; v.f = x;
    return (unsigned short)((v.u + 0x8000u) >> 16);
}

// unpack one bf16 of a packed pair to float (hi is compile-time)
__device__ __forceinline__ float bfpair(unsigned int p, int hi) {
    union { unsigned int u; float f; } v;
    v.u = hi ? (p & 0xffff0000u) : (p << 16);
    return v.f;
}

__device__ __forceinline__ float silu(float x) {
    return x / (1.0f + __expf(-x));
}

// XOR-swizzled half-index into a [rows][128] bf16 tile (256B rows): 16B slots
// XORed with row&7 (m201 st_16x32 pattern) — fragment reads land ~2-way
// bank-aliased (free per m136) with NO padding.
__device__ __forceinline__ int swz(int row, int k) {
    return (row << 7) + (((k >> 3) ^ (row & 7)) << 3) + (k & 7);
}

// same for [rows][64] bf16 tiles (128B rows: XOR row&7 over the 8 16B slots).
__device__ __forceinline__ int swz64(int row, int k) {
    return (row << 6) + (((k >> 3) ^ (row & 7)) << 3) + (k & 7);
}

// ---------------------------------------------------------------------------
// Counting-sort pipeline (scratch lives in d_out; node kernel overwrites d_out
// only at the very end). r10: back to r4's PARALLEL hierarchical scan —
// r9's single-block fused scan was ~16us SLOWER (one CU serially scanning
// 50k bins twice; measured via r4-vs-r9 non-edge delta 181 -> 196us).
// agg zeroing folded into scatter (one fewer dispatch).
// ---------------------------------------------------------------------------
__global__ void hist_kernel(const int* __restrict__ ei, int* __restrict__ cnt,
                            int n_nodes, int n_edges)
{
    for (int e = blockIdx.x * blockDim.x + threadIdx.x; e < n_edges;
         e += gridDim.x * blockDim.x) {
        const int r = min(max(ei[e], 0), n_nodes - 1);
        atomicAdd(&cnt[r], 1);
    }
}

// Local exclusive scan over 256-bin segments; emits per-segment totals.
__global__ __launch_bounds__(256) void scanA_kernel(const int* __restrict__ cnt,
                                                    int* __restrict__ cursor,
                                                    int* __restrict__ btot,
                                                    int nb)
{
    __shared__ int s[256];
    const int t = threadIdx.x;
    const int i = blockIdx.x * 256 + t;
    const int v = (i < nb) ? cnt[i] : 0;
    s[t] = v;
    __syncthreads();
#pragma unroll
    for (int off = 1; off < 256; off <<= 1) {
        const int u = (t >= off) ? s[t - off] : 0;
        __syncthreads();
        s[t] += u;
        __syncthreads();
    }
    if (i < nb) cursor[i] = s[t] - v;           // local exclusive prefix
    if (t == 255) btot[blockIdx.x] = s[255];    // segment total
}

// Single small block: exclusive scan of segment totals.
__global__ __launch_bounds__(256) void scanB_kernel(const int* __restrict__ btot,
                                                    int* __restrict__ boff,
                                                    int nblk)
{
    __shared__ int s[256];
    const int t = threadIdx.x;
    const int v = (t < nblk) ? btot[t] : 0;
    s[t] = v;
    __syncthreads();
#pragma unroll
    for (int off = 1; off < 256; off <<= 1) {
        const int u = (t >= off) ? s[t - off] : 0;
        __syncthreads();
        s[t] += u;
        __syncthreads();
    }
    if (t < nblk) boff[t] = s[t] - v;
}

// One 16B record per sorted edge: {row, col, dist, pad}. Leading grid-stride
// loop zeroes agg (replaces a separate 25.6MB hipMemsetAsync dispatch; the
// edge kernel launches strictly after scatter completes, so ordering holds).
__global__ void scatter_kernel(const int* __restrict__ ei,
                               const float* __restrict__ pos,
                               int* __restrict__ cursor,
                               const int* __restrict__ boff,
                               float4* __restrict__ emeta,
                               float4* __restrict__ aggv,
                               int n_nodes, int n_edges)
{
    const int gtid = blockIdx.x * blockDim.x + threadIdx.x;
    const int gstr = gridDim.x * blockDim.x;

    // zero agg: n_nodes*128 floats = n_nodes*32 float4
    const int nv = n_nodes * 32;
    for (int i = gtid; i < nv; i += gstr)
        aggv[i] = make_float4(0.0f, 0.0f, 0.0f, 0.0f);

    for (int e = gtid; e < n_edges; e += gstr) {
        const int r = min(max(ei[e], 0), n_nodes - 1);
        const int c = min(max(ei[n_edges + e], 0), n_nodes - 1);
        const float dx = pos[r * 3 + 0] - pos[c * 3 + 0];
        const float dy = pos[r * 3 + 1] - pos[c * 3 + 1];
        const float dz = pos[r * 3 + 2] - pos[c * 3 + 2];
        const float dist = sqrtf(dx * dx + dy * dy + dz * dz + 1e-8f);
        const int p = boff[r >> 8] + atomicAdd(&cursor[r], 1);
        emeta[p] = make_float4(__int_as_float(r), __int_as_float(c), dist, 0.0f);
    }
}

// ---------------------------------------------------------------------------
// Edge kernel (r9 body, UNCHANGED — proven 127us): 512 thr = 8 waves, grid
// 256 = 1 block/CU. launch_bounds(512,2) is the only honored VGPR-cap
// spelling (cap 128; waves_per_eu variants all spill — rounds 5-7).
// LDS 64KB: fw2T 32K + fw1T 16K + 8x2K walk buf.
//  * fb1 folded into fw1T bias row k=50 (a1 value 1.0).
//  * contiguous balanced tile range per wave + carry walk (prow,accA,accB
//    persist across tiles; flush only on row transitions). WRITE ~26MB (r9).
// Spill tripwire: FETCH ~142MB, VGPR<=128 (r9: 108).
// ---------------------------------------------------------------------------
template<bool SORTED>
__global__ __launch_bounds__(512, 2) void edge_mfma_kernel(
    const float* __restrict__ h,
    const float* __restrict__ pos,
    const int* __restrict__ ei,
    const float4* __restrict__ emeta,
    const float* __restrict__ fw1,
    const float* __restrict__ fb1,
    const float* __restrict__ fw2,
    const float* __restrict__ fb2,
    float* __restrict__ agg,
    int n_nodes, int n_edges)
{
    __shared__ __attribute__((aligned(16))) unsigned short fw2T[128 * 128];
    __shared__ __attribute__((aligned(16))) unsigned short fw1T[128 * 64];
    __shared__ __attribute__((aligned(16))) unsigned short tbuf[8 * 16 * 64];

    const int tid  = threadIdx.x;
    const int wave = tid >> 6;
    const int lane = tid & 63;
    const int l15  = lane & 15;
    const int quad = lane >> 4;

    // stage fw2 transposed+swizzled (bf16): fw2T[(n,k)] = fw2[k][n]
    for (int idx = tid; idx < HIDDEN * HIDDEN; idx += 512) {
        const int k = idx >> 7, n = idx & 127;
        fw2T[swz(n, k)] = f2bf(fw2[idx]);
    }
    // stage fw1 transposed+swizzled; row k=50 := fb1 (bias row), rows>50 zero
    for (int idx = tid; idx < HIDDEN * 64; idx += 512) {
        const int n = idx >> 6, k = idx & 63;
        const float v = (k < NUM_RBF) ? fw1[k * HIDDEN + n]
                      : (k == NUM_RBF ? fb1[n] : 0.0f);
        fw1T[swz64(n, k)] = f2bf(v);
    }

    // fb2 packed bf16 (4 VGPR)
    unsigned int fb2p[4];
#pragma unroll
    for (int p = 0; p < 4; ++p) {
        fb2p[p] = ((unsigned int)f2bf(fb2[(p * 2 + 1) * 16 + l15]) << 16) |
                  (unsigned int)f2bf(fb2[(p * 2) * 16 + l15]);
    }

    __syncthreads();   // fw2T/fw1T ready; no barriers inside the loop

    unsigned short* twave = &tbuf[wave * 16 * 64];
    const int tiles = (n_edges + 15) >> 4;

    // balanced CONTIGUOUS range for this wave
    const int nw  = gridDim.x * 8;
    const int wid = blockIdx.x * 8 + wave;
    const int qt  = tiles / nw, rmd = tiles % nw;
    const int t0  = wid * qt + min(wid, rmd);
    const int t1  = t0 + qt + (wid < rmd ? 1 : 0);

    // ---- prefetch first tile's meta (sorted path) ----
    float4 nm = make_float4(0.0f, 0.0f, 0.0f, 0.0f);
    bool   nval = false;
    if (SORTED && t0 < t1) {
        const int e = t0 * 16 + l15;
        nval = (e < n_edges);
        nm = emeta[min(e, n_edges - 1)];
    }

    // carry state (wave-uniform prow; per-lane half-channel accumulators)
    int prow = -1;
    float accA = 0.0f, accB = 0.0f;

    for (int tile = t0; tile < t1; ++tile) {
        // ---- edge meta: lane handles edge m = l15 (x4 redundant) ----
        int row, col; float dist; bool valid;
        if (SORTED) {
            row = __float_as_int(nm.x); col = __float_as_int(nm.y);
            dist = nm.z; valid = nval;
            const int tn = tile + 1;
            if (tn < t1) {
                const int e = tn * 16 + l15;
                nval = (e < n_edges);
                nm = emeta[min(e, n_edges - 1)];
            }
        } else {
            const int e = tile * 16 + l15;
            valid = (e < n_edges);
            const int eidx = valid ? e : (n_edges - 1);
            row = min(max(ei[eidx], 0), n_nodes - 1);
            col = min(max(ei[n_edges + eidx], 0), n_nodes - 1);
            const float dx = pos[row * 3 + 0] - pos[col * 3 + 0];
            const float dy = pos[row * 3 + 1] - pos[col * 3 + 1];
            const float dz = pos[row * 3 + 2] - pos[col * 3 + 2];
            dist = sqrtf(dx * dx + dy * dy + dz * dz + 1e-8f);
        }
        const float cut = (valid && dist <= CUTOFF)
            ? 0.5f * (__cosf(PI_F * dist * (1.0f / CUTOFF)) + 1.0f) : 0.0f;

        // broadcast to C-layout owners (edge = quad*4 + r) via shfl
        int mrow[4], mcol[4]; float mcut[4];
#pragma unroll
        for (int r = 0; r < 4; ++r) {
            const int src = quad * 4 + r;      // lanes 0..15 hold edges 0..15
            if (!SORTED) mrow[r] = __shfl(row, src);
            mcol[r] = __shfl(col, src);
            mcut[r] = __shfl(cut, src);
        }

        // ---- EARLY h gather, packed to bf16 pairs (16 VGPR; the message is
        // rounded to bf16 downstream anyway) ----
        unsigned int hv2[4][4];
#pragma unroll
        for (int r = 0; r < 4; ++r) {
            const float* hp = &h[(size_t)mcol[r] * HIDDEN + l15];
#pragma unroll
            for (int p = 0; p < 4; ++p) {
                const float f0 = hp[p * 32];
                const float f1 = hp[p * 32 + 16];
                hv2[r][p] = ((unsigned int)f2bf(f1) << 16) |
                            (unsigned int)f2bf(f0);
            }
        }

        // ---- A1 fragments: RBFs in-register; k==50 is the BIAS row (1.0) ----
        short8 a1[2];
#pragma unroll
        for (int kit = 0; kit < 2; ++kit) {
            short8 f;
#pragma unroll
            for (int j = 0; j < 8; ++j) {
                const int k = kit * 32 + quad * 8 + j;
                const float x = (dist - OFF_STEP * (float)k) * INV_WIDTH;
                const float rv = (k < NUM_RBF) ? __expf(-0.5f * x * x)
                               : (k == NUM_RBF ? 1.0f : 0.0f);
                f[j] = (short)f2bf(rv);
            }
            a1[kit] = f;
        }

        // ---- layer 1 -> silu -> tbuf in TWO 64-chan halves; A2 frags pulled
        // into regs after each half (wave-private LDS store->read idiom) ----
        short8 a2[4];
#pragma unroll
        for (int half = 0; half < 2; ++half) {
#pragma unroll
            for (int nt2 = 0; nt2 < 4; ++nt2) {
                const int nt = half * 4 + nt2;
                const short8 bA =
                    *(const short8*)&fw1T[swz64(nt * 16 + l15, quad * 8)];
                const short8 bB =
                    *(const short8*)&fw1T[swz64(nt * 16 + l15, 32 + quad * 8)];
                floatx4 c = {0.0f, 0.0f, 0.0f, 0.0f};   // bias via k=50 row
                c = __builtin_amdgcn_mfma_f32_16x16x32_bf16(a1[0], bA, c, 0, 0, 0);
                c = __builtin_amdgcn_mfma_f32_16x16x32_bf16(a1[1], bB, c, 0, 0, 0);
#pragma unroll
                for (int r = 0; r < 4; ++r)
                    twave[swz64(quad * 4 + r, nt2 * 16 + l15)] = f2bf(silu(c[r]));
            }
            a2[half * 2]     = *(const short8*)&twave[swz64(l15, quad * 8)];
            a2[half * 2 + 1] = *(const short8*)&twave[swz64(l15, 32 + quad * 8)];
        }

        // ---- walk mask: bit i = (row[i] != row[i-1]), i>=1; i==0 boundary
        // is the runtime carry check vs prow ----
        unsigned int mask = 0;
        int r0 = 0;
        if (SORTED) {
            const int pr = __shfl(row, (l15 > 0) ? (l15 - 1) : 0);
            const unsigned long long bal =
                __ballot((l15 > 0) && (row != pr));
            mask = (unsigned int)bal & 0xFFFFu;
            r0 = __shfl(row, 0);
        }

        // ---- layer 2 + cutoff*h epilogue, per 64-chan half; carry walk ----
#pragma unroll
        for (int half = 0; half < 2; ++half) {
#pragma unroll
            for (int nt2 = 0; nt2 < 4; ++nt2) {
                const int nt = half * 4 + nt2;
                const float b0 = bfpair(fb2p[nt >> 1], nt & 1);
                floatx4 c = {b0, b0, b0, b0};
#pragma unroll
                for (int kit = 0; kit < 4; ++kit) {
                    const short8 b =
                        *(const short8*)&fw2T[swz(nt * 16 + l15, kit * 32 + quad * 8)];
                    c = __builtin_amdgcn_mfma_f32_16x16x32_bf16(a2[kit], b, c, 0, 0, 0);
                }
                const int chan = nt * 16 + l15;
#pragma unroll
                for (int r = 0; r < 4; ++r) {
                    const float val = c[r] * mcut[r] * bfpair(hv2[r][nt >> 1], nt & 1);
                    if (SORTED) {
                        twave[swz64(quad * 4 + r, nt2 * 16 + l15)] = f2bf(val);
                    } else {
                        atomicAdd(&agg[mrow[r] * HIDDEN + chan], val);
                    }
                }
            }

            if (SORTED) {
                const int gchan = half * 64 + lane;   // this lane's channel
                float acc = half ? accB : accA;
                int pr = prow;                        // both halves replay the
#pragma unroll                                        // same boundary sequence
                for (int i = 0; i < 16; ++i) {
                    union { unsigned int u; float f; } v;
                    v.u = (unsigned int)twave[swz64(i, lane)] << 16;
                    const bool bnd = (i == 0) ? (r0 != pr)
                                              : ((mask >> i) & 1u);
                    if (bnd) {                        // wave-uniform branch
                        if (pr >= 0)
                            atomicAdd(&agg[pr * HIDDEN + gchan], acc);
                        acc = 0.0f;
                        pr = __shfl(row, i);
                    }
                    acc += v.f;
                }
                if (half) { accB = acc; prow = pr; }
                else      { accA = acc; }
            }
        }
    }

    // ---- final carry flush ----
    if (SORTED && prow >= 0) {
        atomicAdd(&agg[prow * HIDDEN + lane],      accA);
        atomicAdd(&agg[prow * HIDDEN + 64 + lane], accB);
    }
}

// ---------------------------------------------------------------------------
// Node kernel (MFMA): out = h + silu(agg@iw1+b1)@iw2+b2. Grid 256.
// ---------------------------------------------------------------------------
__global__ __launch_bounds__(256) void node_mfma_kernel(
    const float* __restrict__ h,
    const float* __restrict__ agg,
    const float* __restrict__ iw1,
    const float* __restrict__ ib1,
    const float* __restrict__ iw2,
    const float* __restrict__ ib2,
    float* __restrict__ out,
    int n_nodes)
{
    __shared__ __attribute__((aligned(16))) unsigned short w2T[128 * 128];
    __shared__ __attribute__((aligned(16))) unsigned short tbuf[4 * 16 * 128];

    const int tid  = threadIdx.x;
    const int wave = tid >> 6;
    const int lane = tid & 63;
    const int l15  = lane & 15;
    const int quad = lane >> 4;

    for (int idx = tid; idx < HIDDEN * HIDDEN; idx += 256) {
        const int k = idx >> 7, n = idx & 127;
        w2T[swz(n, k)] = f2bf(iw2[idx]);
    }

    short8 b1[4][8];
#pragma unroll
    for (int kit = 0; kit < 4; ++kit)
#pragma unroll
        for (int nt = 0; nt < 8; ++nt) {
            short8 f;
#pragma unroll
            for (int j = 0; j < 8; ++j) {
                const int k = kit * 32 + quad * 8 + j;
                f[j] = (short)f2bf(iw1[k * HIDDEN + nt * 16 + l15]);
            }
            b1[kit][nt] = f;
        }

    float ib1v[8], ib2v[8];
#pragma unroll
    for (int nt = 0; nt < 8; ++nt) {
        ib1v[nt] = ib1[nt * 16 + l15];
        ib2v[nt] = ib2[nt * 16 + l15];
    }

    __syncthreads();

    unsigned short* twave = &tbuf[wave * 16 * 128];
    const int tiles = (n_nodes + 15) >> 4;

    for (int tile = blockIdx.x * 4 + wave; tile < tiles; tile += gridDim.x * 4) {
        const int m0 = tile * 16;

        const int mA = min(m0 + l15, n_nodes - 1);
        short8 a1[4];
#pragma unroll
        for (int kit = 0; kit < 4; ++kit) {
            const float* p = &agg[(size_t)mA * HIDDEN + kit * 32 + quad * 8];
            short8 f;
#pragma unroll
            for (int j = 0; j < 8; ++j) f[j] = (short)f2bf(p[j]);
            a1[kit] = f;
        }

        int mo[4]; float hres[4][8];
#pragma unroll
        for (int r = 0; r < 4; ++r) {
            mo[r] = m0 + quad * 4 + r;
            const int mc = min(mo[r], n_nodes - 1);
#pragma unroll
            for (int nt = 0; nt < 8; ++nt)
                hres[r][nt] = h[(size_t)mc * HIDDEN + nt * 16 + l15];
        }

#pragma unroll
        for (int nt = 0; nt < 8; ++nt) {
            floatx4 c = {ib1v[nt], ib1v[nt], ib1v[nt], ib1v[nt]};
#pragma unroll
            for (int kit = 0; kit < 4; ++kit)
                c = __builtin_amdgcn_mfma_f32_16x16x32_bf16(a1[kit], b1[kit][nt], c, 0, 0, 0);
#pragma unroll
            for (int r = 0; r < 4; ++r)
                twave[swz(quad * 4 + r, nt * 16 + l15)] = f2bf(silu(c[r]));
        }

        short8 a2[4];
#pragma unroll
        for (int kit = 0; kit < 4; ++kit)
            a2[kit] = *(const short8*)&twave[swz(l15, kit * 32 + quad * 8)];

#pragma unroll
        for (int nt = 0; nt < 8; ++nt) {
            floatx4 c = {ib2v[nt], ib2v[nt], ib2v[nt], ib2v[nt]};
#pragma unroll
            for (int kit = 0; kit < 4; ++kit) {
                const short8 b =
                    *(const short8*)&w2T[swz(nt * 16 + l15, kit * 32 + quad * 8)];
                c = __builtin_amdgcn_mfma_f32_16x16x32_bf16(a2[kit], b, c, 0, 0, 0);
            }
            const int chan = nt * 16 + l15;
#pragma unroll
            for (int r = 0; r < 4; ++r)
                if (mo[r] < n_nodes)
                    out[(size_t)mo[r] * HIDDEN + chan] = hres[r][nt] + c[r];
        }
    }
}

extern "C" void kernel_launch(void* const* d_in, const int* in_sizes, int n_in,
                              void* d_out, int out_size, void* d_ws, size_t ws_size,
                              hipStream_t stream)
{
    const float* h   = (const float*)d_in[0];
    const float* pos = (const float*)d_in[1];
    const int*   ei  = (const int*)d_in[2];
    const float* fw1 = (const float*)d_in[3];
    const float* fb1 = (const float*)d_in[4];
    const float* fw2 = (const float*)d_in[5];
    const float* fb2 = (const float*)d_in[6];
    const float* iw1 = (const float*)d_in[7];
    const float* ib1 = (const float*)d_in[8];
    const float* iw2 = (const float*)d_in[9];
    const float* ib2 = (const float*)d_in[10];
    float* out = (float*)d_out;

    const int n_nodes = in_sizes[0] / HIDDEN;
    const int n_edges = in_sizes[2] / 2;
    const int nscan   = (n_nodes + 255) >> 8;   // scanA blocks (<=256 required)

    const size_t need = (size_t)n_nodes * HIDDEN * sizeof(float);
    const bool use_ws = (d_ws != nullptr) && (ws_size >= need);

    // sort scratch layout in d_out (ints): cnt[nb] cursor[nb] btot[256]
    // boff[256] emeta[4*E] (emeta 16B-aligned)
    const size_t moff = (((size_t)2 * n_nodes + 512) + 3) & ~(size_t)3;
    const size_t scratch_ints = moff + (size_t)4 * n_edges;
    const bool can_sort = use_ws && nscan <= 256 &&
                          ((size_t)out_size >= scratch_ints);

    if (can_sort) {
        float*  agg    = (float*)d_ws;
        int*    base   = (int*)d_out;
        int*    cnt    = base;
        int*    cursor = base + n_nodes;
        int*    btot   = base + 2 * n_nodes;
        int*    boff   = btot + 256;
        float4* emeta  = (float4*)(base + moff);

        hipMemsetAsync(cnt, 0, (size_t)n_nodes * sizeof(int), stream);

        hist_kernel<<<1024, 256, 0, stream>>>(ei, cnt, n_nodes, n_edges);
        scanA_kernel<<<nscan, 256, 0, stream>>>(cnt, cursor, btot, n_nodes);
        scanB_kernel<<<1, 256, 0, stream>>>(btot, boff, nscan);
        scatter_kernel<<<1024, 256, 0, stream>>>(ei, pos, cursor, boff,
                                                 emeta, (float4*)agg,
                                                 n_nodes, n_edges);

        // 256 blocks x 8 waves = 1 block/CU; contiguous balanced tile ranges
        edge_mfma_kernel<true><<<256, 512, 0, stream>>>(
            h, pos, ei, emeta,
            fw1, fb1, fw2, fb2, agg, n_nodes, n_edges);

        node_mfma_kernel<<<256, 256, 0, stream>>>(h, agg, iw1, ib1, iw2, ib2,
                                                  out, n_nodes);
    } else {
        float* agg = use_ws ? (float*)d_ws : out;
        hipMemsetAsync(agg, 0, need, stream);
        edge_mfma_kernel<false><<<256, 512, 0, stream>>>(
            h, pos, ei, nullptr,
            fw1, fb1, fw2, fb2, agg, n_nodes, n_edges);
        node_mfma_kernel<<<256, 256, 0, stream>>>(h, agg, iw1, ib1, iw2, ib2,
                                                  out, n_nodes);
    }
}